// Round 2
// baseline (418.888 us; speedup 1.0000x reference)
//
#include <hip/hip_runtime.h>

// ShiftingLayer: out[j] = (0 <= j-offset < n) ? x[j-offset] : 0,
// offset = trunc(w_row + row_length*w_col)  (= 8193 for the given inputs).
// Pure memory-bound shifted copy: 268 MB read + 268 MB write.
//
// Key perf point: offset % 4 != 0, so the source read for an aligned
// float4 store is only dword-aligned. gfx950 global_load_dwordx4 requires
// only dword alignment, so we use an align(4) vector type for the bulk
// path (one dwordx4 per lane) and take the guarded scalar path only in
// the ~2 boundary waves.

typedef float f4 __attribute__((ext_vector_type(4)));
typedef f4 __attribute__((aligned(4))) f4_a4;  // 4-byte-aligned float4 view

__global__ __launch_bounds__(256) void ShiftingLayer_shift_kernel(
    const float* __restrict__ x,
    const float* __restrict__ w_row,
    const float* __restrict__ w_col,
    const int*   __restrict__ row_length,
    float* __restrict__ out,
    long long n)
{
    // Scalar offset computed on-device (scalars are 1-element arrays).
    // float->int truncates toward zero, matching numpy astype(int32).
    const long long offset =
        (long long)(int)(w_row[0] + (float)row_length[0] * w_col[0]);

    const long long j = ((long long)blockIdx.x * blockDim.x + threadIdx.x) * 4;
    if (j >= n) return;

    const long long s = j - offset;

    f4 v;
    if (s >= 0 && s + 3 < n) {
        // Bulk path: one unaligned (dword-aligned) vector load.
        v = *reinterpret_cast<const f4_a4*>(x + s);
    } else {
        // Boundary path: per-element guards (runs for <=2 waves total).
        v.x = (s + 0 >= 0 && s + 0 < n) ? x[s + 0] : 0.0f;
        v.y = (s + 1 >= 0 && s + 1 < n) ? x[s + 1] : 0.0f;
        v.z = (s + 2 >= 0 && s + 2 < n) ? x[s + 2] : 0.0f;
        v.w = (s + 3 >= 0 && s + 3 < n) ? x[s + 3] : 0.0f;
    }

    // n is a multiple of 4, store is 16B-aligned and covers every element.
    *reinterpret_cast<f4*>(out + j) = v;
}

extern "C" void kernel_launch(void* const* d_in, const int* in_sizes, int n_in,
                              void* d_out, int out_size, void* d_ws, size_t ws_size,
                              hipStream_t stream)
{
    const float* x     = (const float*)d_in[0];
    const float* w_row = (const float*)d_in[1];
    const float* w_col = (const float*)d_in[2];
    const int*   rlen  = (const int*)d_in[3];
    float* out = (float*)d_out;

    const long long n = (long long)out_size;  // 67,108,864

    const int block = 256;
    const long long vecs = (n + 3) / 4;
    const int grid = (int)((vecs + block - 1) / block);

    ShiftingLayer_shift_kernel<<<grid, block, 0, stream>>>(
        x, w_row, w_col, rlen, out, n);
}